// Round 7
// baseline (5092.171 us; speedup 1.0000x reference)
//
#include <hip/hip_runtime.h>
#include <hip/hip_bf16.h>
#include <stdint.h>

// Problem constants
#define N_B     64
#define T_STEPS 1024
#define T1      1025
#define VOCAB   10000
#define DIM     512
#define HID     512
#define FOURH   2048
#define SBLK    64      // scan blocks: 8 groups (8 batch rows each) x 8 dim-slices
#define RPG     8       // batch rows per group
#define WAVES   4       // waves per scan block (16 dims each)
#define LPAD    520     // u16 row stride in LDS h planes (1040 B)
#define FLGSTR  32      // u32 stride between per-wave flags (128 B line each)

typedef unsigned short u16;
typedef unsigned int   u32;
typedef unsigned long long u64;
typedef short bf16x8 __attribute__((ext_vector_type(8)));   // 8 bf16 = 4 VGPRs
typedef float f32x4  __attribute__((ext_vector_type(4)));   // 16x16 MFMA acc
typedef float f32x16 __attribute__((ext_vector_type(16)));  // 32x32 MFMA acc
typedef u32  u32x4  __attribute__((ext_vector_type(4)));

__device__ __forceinline__ float bf2f(u16 x){
  union { u32 u; float f; } v; v.u = ((u32)x) << 16; return v.f;
}
__device__ __forceinline__ u16 f2bf(float f){
  union { float f; u32 u; } v; v.f = f;
  u32 u = v.u;
  return (u16)((u + 0x7FFFu + ((u >> 16) & 1u)) >> 16);  // RNE
}
__device__ __forceinline__ bf16x8 ldfrag(const u16* p){
  union { u32x4 q; bf16x8 s; } v; v.q = *(const u32x4*)p; return v.s;
}
__device__ __forceinline__ float fsig(float x){
  return 1.0f / (1.0f + exp2f(x * -1.44269504f));
}
__device__ __forceinline__ float ftanh(float x){
  return 1.0f - 2.0f / (1.0f + exp2f(x * 2.88539008f));  // saturates at +/-1
}
// pack h into u32: low16 = bf16 hi, high16 = bf16 lo (residual)
__device__ __forceinline__ u32 packhl(float h){
  u32 hb = f2bf(h);
  float rem = h - bf2f((u16)hb);
  u32 lb = f2bf(rem);
  return hb | (lb << 16);
}

// ---- transpose+convert Wx, Wh (512 x 2048 fp32) -> bf16 (2048 x 512) ----
__global__ void k_transpose(const float* __restrict__ Wx, const float* __restrict__ Wh,
                            u16* __restrict__ WxT, u16* __restrict__ WhT){
  int b = blockIdx.x;
  const float* src = Wx; u16* dst = WxT;
  if (b >= 512){ src = Wh; dst = WhT; b -= 512; }
  int id = b * 256 + threadIdx.x;       // 131072 ids: 2048 cols x 64 k-chunks
  int n  = id & (FOURH - 1);            // source col (consecutive per lane -> coalesced)
  int kc = (id >> 11) << 3;             // k chunk of 8
  u32 w[4];
  #pragma unroll
  for (int j = 0; j < 4; j++){
    u32 lo = (u32)f2bf(src[(kc + 2*j    ) * FOURH + n]);
    u32 hi = (u32)f2bf(src[(kc + 2*j + 1) * FOURH + n]);
    w[j] = lo | (hi << 16);
  }
  uint4 q; q.x = w[0]; q.y = w[1]; q.z = w[2]; q.w = w[3];
  *(uint4*)(dst + n * DIM + kc) = q;
}

// ---- convert W_embed (10000 x 512 fp32) -> bf16, same layout ----
__global__ void k_wemb(const float* __restrict__ Wemb, u16* __restrict__ We16){
  int i = blockIdx.x * 256 + threadIdx.x;        // 2,560,000 ids, 2 elems each
  float2 f = *(const float2*)(Wemb + 2 * i);
  u32 pk = (u32)f2bf(f.x) | ((u32)f2bf(f.y) << 16);
  *(u32*)(We16 + 2 * i) = pk;
}

// ---- init flags ----
__global__ void k_init(u32* flags){
  int i = blockIdx.x * 256 + threadIdx.x;   // 8192 = SBLK*WAVES*FLGSTR
  flags[i] = 0;
}

// ---- E = W_embed @ Wx + b  (10000 x 2048, bf16) ----
__launch_bounds__(256)
__global__ void k_egemm(const u16* __restrict__ Wemb, const u16* __restrict__ WxT,
                        const float* __restrict__ bias, u16* __restrict__ E){
  int nb = blockIdx.x;            // 0..15  -> cols nb*128
  int mb = blockIdx.y;            // 0..78  -> rows mb*128
  int wv   = threadIdx.x >> 6;
  int lane = threadIdx.x & 63;
  int l31 = lane & 31, hi5 = lane >> 5;
  int mrow = mb * 128 + wv * 32 + l31;
  int mcl  = mrow < VOCAB ? mrow : VOCAB - 1;
  const u16* ap  = Wemb + (u32)mcl * DIM + hi5 * 8;
  const u16* bp0 = WxT + (u32)(nb * 128 +  0 + l31) * DIM + hi5 * 8;
  const u16* bp1 = bp0 + 32 * DIM;
  const u16* bp2 = bp0 + 64 * DIM;
  const u16* bp3 = bp0 + 96 * DIM;
  f32x16 acc[4] = {};
  for (int ks = 0; ks < 32; ks++){
    bf16x8 av = ldfrag(ap);  ap  += 16;
    bf16x8 b0 = ldfrag(bp0); bp0 += 16;
    bf16x8 b1 = ldfrag(bp1); bp1 += 16;
    bf16x8 b2 = ldfrag(bp2); bp2 += 16;
    bf16x8 b3 = ldfrag(bp3); bp3 += 16;
    acc[0] = __builtin_amdgcn_mfma_f32_32x32x16_bf16(av, b0, acc[0], 0, 0, 0);
    acc[1] = __builtin_amdgcn_mfma_f32_32x32x16_bf16(av, b1, acc[1], 0, 0, 0);
    acc[2] = __builtin_amdgcn_mfma_f32_32x32x16_bf16(av, b2, acc[2], 0, 0, 0);
    acc[3] = __builtin_amdgcn_mfma_f32_32x32x16_bf16(av, b3, acc[3], 0, 0, 0);
  }
  int rbase = mb * 128 + wv * 32 + 4 * hi5;
  #pragma unroll
  for (int nt = 0; nt < 4; nt++){
    int col = nb * 128 + nt * 32 + l31;
    float bv = bias[col];
    #pragma unroll
    for (int r = 0; r < 16; r++){
      int row = rbase + (r & 3) + 8 * (r >> 2);
      if (row < VOCAB) E[(u32)row * FOURH + col] = f2bf(acc[nt][r] + bv);
    }
  }
}

// ---- persistent LSTM scan: batch-group replication, 1-barrier exchange ----
// 64 blocks x 256 threads (4 waves). group g = bid&7 owns rows [g*8,g*8+8);
// slice s = bid>>3 computes dims [s*64,s*64+64). Wave w owns 16 dims
// (4 subtiles), Wh slice in 256 VGPRs (loaded once).
// LDS rationale: every wave reads ALL of h (B-operand shared, A per-wave),
// so LDS instr count scales with wave count -> 4 waves halves R6's LDS term.
// Exchange protocol (1 syncthreads/step): per-WAVE flags; each wave:
//   cell -> publish own dims (MALL write-through atomics) -> s_waitcnt
//   vmcnt(0) (wave-local) -> flag=t+1 -> out stores + E prefetch (off
//   critical path) -> poll all 32 group flags -> stage own 2 rows -> barrier.
// Safety: monotone flags; flag>=t+1 from wave X => X finished K-loop(t)
// (publish follows cell follows K-loop), so staging hls / overwriting hbuf
// parity is race-free; own block's waves are in the poll set.
// MFMA 16x16x32 (m89-verified): A row=l&15 -> gate col (li&3)*512+dim,
// k=(l>>4)*8+j; B col=l&15 (n=col&7, cols 8-15 dup), same k;
// C/D col=l&15 -> n, row=(l>>4)*4+reg -> gate=reg, dim=dwW+sub*4+lg4.
__launch_bounds__(256, 1)
__global__ void k_scan(const int* __restrict__ cap, const u16* __restrict__ E,
                       const u16* __restrict__ WhT, const float* __restrict__ h0,
                       u32* __restrict__ hbuf, u32* flags, float* __restrict__ out){
  __shared__ __align__(16) u16 hls[2][RPG][LPAD];   // [0]=hi plane, [1]=lo plane

  const int bid = blockIdx.x;
  const int g = bid & 7, s = bid >> 3;
  const int tid = threadIdx.x;            // 0..255
  const int w = tid >> 6, l = tid & 63;
  const int li = l & 15, lg4 = l >> 4;
  const int n  = li & 7;                  // batch row within group
  const int gr0 = g * RPG;                // global row base
  const int dwW = s * 64 + w * 16;        // wave's dim base (16 dims)

  // ---- Wh slice -> 256 VGPRs (once) ----
  const int gate = li & 3, doff = li >> 2;
  bf16x8 wreg[4][16];
  #pragma unroll
  for (int sub = 0; sub < 4; sub++){
    const u16* wb = WhT + (u32)(gate * 512 + dwW + sub * 4 + doff) * DIM + lg4 * 8;
    #pragma unroll
    for (int ks = 0; ks < 16; ks++)
      wreg[sub][ks] = ldfrag(wb + ks * 32);
  }

  // ---- stage h0 into LDS planes (thread: row r, 16 dims) ----
  {
    int r = tid >> 5, d0 = (tid & 31) * 16;
    const float* hp = h0 + (u32)(gr0 + r) * HID + d0;
    u16 hh[16], ll[16];
    #pragma unroll
    for (int k2 = 0; k2 < 16; k2++){
      float f = hp[k2];
      u16 hb = f2bf(f);
      hh[k2] = hb;
      ll[k2] = f2bf(f - bf2f(hb));
    }
    u32x4 qh0, qh1, ql0, ql1;
    #pragma unroll
    for (int j = 0; j < 4; j++){
      qh0[j] = (u32)hh[2*j]   | ((u32)hh[2*j+1] << 16);
      qh1[j] = (u32)hh[8+2*j] | ((u32)hh[8+2*j+1] << 16);
      ql0[j] = (u32)ll[2*j]   | ((u32)ll[2*j+1] << 16);
      ql1[j] = (u32)ll[8+2*j] | ((u32)ll[8+2*j+1] << 16);
    }
    *(u32x4*)&hls[0][r][d0]     = qh0;
    *(u32x4*)&hls[0][r][d0 + 8] = qh1;
    *(u32x4*)&hls[1][r][d0]     = ql0;
    *(u32x4*)&hls[1][r][d0 + 8] = ql1;
  }
  __syncthreads();

  // ---- E prefetch for t=0 (cap pipeline 2-deep) ----
  u32 ev[4][4];   // [sub][gate]
  {
    int cap0 = cap[(u32)(gr0 + n) * T1];
    #pragma unroll
    for (int sub = 0; sub < 4; sub++)
      #pragma unroll
      for (int gt = 0; gt < 4; gt++)
        ev[sub][gt] = (u32)E[(u32)cap0 * FOURH + gt * 512 + dwW + sub * 4 + lg4];
  }
  int capn1 = cap[(u32)(gr0 + n) * T1 + 1];

  float cst[4] = {0.f, 0.f, 0.f, 0.f};

  for (int t = 0; t < T_STEPS; t++){
    // ---- K-loop: acc = h . WhSlice (hi + lo planes) ----
    f32x4 acc[4] = {}, acc2[4] = {};
    #pragma unroll
    for (int ks = 0; ks < 16; ks++){
      bf16x8 bh = ldfrag(&hls[0][n][ks * 32 + lg4 * 8]);
      bf16x8 bl = ldfrag(&hls[1][n][ks * 32 + lg4 * 8]);
      #pragma unroll
      for (int sub = 0; sub < 4; sub++)
        acc[sub]  = __builtin_amdgcn_mfma_f32_16x16x32_bf16(wreg[sub][ks], bh, acc[sub], 0, 0, 0);
      #pragma unroll
      for (int sub = 0; sub < 4; sub++)
        acc2[sub] = __builtin_amdgcn_mfma_f32_16x16x32_bf16(wreg[sub][ks], bl, acc2[sub], 0, 0, 0);
    }

    // ---- LSTM cell (gate = reg; dim = dwW + sub*4 + lg4; row n) ----
    float hv[4];
    #pragma unroll
    for (int sub = 0; sub < 4; sub++){
      float ai = acc[sub][0] + acc2[sub][0] + bf2f((u16)ev[sub][0]);
      float af = acc[sub][1] + acc2[sub][1] + bf2f((u16)ev[sub][1]);
      float ao = acc[sub][2] + acc2[sub][2] + bf2f((u16)ev[sub][2]);
      float ag = acc[sub][3] + acc2[sub][3] + bf2f((u16)ev[sub][3]);
      float ig = fsig(ai), fg = fsig(af), og = fsig(ao), gg = ftanh(ag);
      cst[sub] = fg * cst[sub] + ig * gg;
      hv[sub] = og * ftanh(cst[sub]);
    }

    const int ph = (t + 1) & 1;
    if (t < T_STEPS - 1){
      // ---- publish h_{t+1}: u64 pairs (dims d,d+1), d+1 via shfl ----
      u32 pk[4], pr[4];
      #pragma unroll
      for (int sub = 0; sub < 4; sub++){
        pk[sub] = packhl(hv[sub]);
        pr[sub] = (u32)__shfl_down((int)pk[sub], 16);
      }
      if (li < 8 && (lg4 & 1) == 0){
        u32* dst = hbuf + (u32)ph * (N_B * HID) + (u32)(gr0 + n) * HID + dwW + lg4;
        #pragma unroll
        for (int sub = 0; sub < 4; sub++)
          __hip_atomic_store((u64*)(dst + sub * 4),
                             (u64)pk[sub] | ((u64)pr[sub] << 32),
                             __ATOMIC_RELAXED, __HIP_MEMORY_SCOPE_AGENT);
      }
      // wave-local ordering: publishes at coherence point before flag
      asm volatile("s_waitcnt vmcnt(0)" ::: "memory");
      __hip_atomic_store(&flags[(u32)(bid * WAVES + w) * FLGSTR], (u32)(t + 1),
                         __ATOMIC_RELAXED, __HIP_MEMORY_SCOPE_AGENT);
    }

    // ---- off critical path: out stores (fp32 pairs) + E prefetch ----
    {
      float hr[4];
      #pragma unroll
      for (int sub = 0; sub < 4; sub++) hr[sub] = __shfl_down(hv[sub], 16);
      if (li < 8 && (lg4 & 1) == 0){
        float* ob = out + (u32)(gr0 + n) * (T_STEPS * HID) + (u32)t * HID + dwW + lg4;
        #pragma unroll
        for (int sub = 0; sub < 4; sub++){
          union { float f[2]; u64 u; } o2;
          o2.f[0] = hv[sub]; o2.f[1] = hr[sub];
          __builtin_nontemporal_store(o2.u, (u64*)(ob + sub * 4));
        }
      }
    }

    if (t < T_STEPS - 1){
      // E prefetch for t+1 (independent; hides under poll)
      #pragma unroll
      for (int sub = 0; sub < 4; sub++)
        #pragma unroll
        for (int gt = 0; gt < 4; gt++)
          ev[sub][gt] = (u32)E[(u32)capn1 * FOURH + gt * 512 + dwW + sub * 4 + lg4];
      int tn = t + 2; if (tn > T_STEPS) tn = T_STEPS;
      capn1 = cap[(u32)(gr0 + n) * T1 + tn];

      // ---- poll all 32 group flags (every wave; lane l<32: peer s'=l>>2, wave l&3) ----
      {
        const u32 want = (u32)(t + 1);
        const u32* fp = &flags[(u32)(((l >> 2) * 8 + g) * WAVES + (l & 3)) * FLGSTR];
        u32 v;
        do {
          v = (l < 32)
                ? __hip_atomic_load(fp, __ATOMIC_RELAXED, __HIP_MEMORY_SCOPE_AGENT)
                : want;
        } while (__ballot(v < want));
      }

      // ---- stage h_{t+1} -> LDS planes (thread: row r = tid>>5, 16 dims) ----
      {
        int r = tid >> 5, d0 = (tid & 31) * 16;
        const u32* src = hbuf + (u32)ph * (N_B * HID) + (u32)(gr0 + r) * HID + d0;
        u32 p[16];
        #pragma unroll
        for (int i = 0; i < 8; i++){
          u64 a = __hip_atomic_load((const u64*)(src + 2 * i),
                                    __ATOMIC_RELAXED, __HIP_MEMORY_SCOPE_AGENT);
          p[2*i] = (u32)a; p[2*i+1] = (u32)(a >> 32);
        }
        u32x4 qh0, qh1, ql0, ql1;
        #pragma unroll
        for (int j = 0; j < 4; j++){
          qh0[j] = (p[2*j]   & 0xFFFFu) | (p[2*j+1] << 16);
          qh1[j] = (p[8+2*j] & 0xFFFFu) | (p[8+2*j+1] << 16);
          ql0[j] = (p[2*j]   >> 16) | (p[2*j+1] & 0xFFFF0000u);
          ql1[j] = (p[8+2*j] >> 16) | (p[8+2*j+1] & 0xFFFF0000u);
        }
        *(u32x4*)&hls[0][r][d0]     = qh0;
        *(u32x4*)&hls[0][r][d0 + 8] = qh1;
        *(u32x4*)&hls[1][r][d0]     = ql0;
        *(u32x4*)&hls[1][r][d0 + 8] = ql1;
      }
      __syncthreads();   // the ONE barrier: all rows staged before next K-loop
    }
  }
}

extern "C" void kernel_launch(void* const* d_in, const int* in_sizes, int n_in,
                              void* d_out, int out_size, void* d_ws, size_t ws_size,
                              hipStream_t stream){
  const int*   cap  = (const int*)d_in[0];
  const float* h0   = (const float*)d_in[1];
  const float* Wemb = (const float*)d_in[2];
  const float* Wx   = (const float*)d_in[3];
  const float* Wh   = (const float*)d_in[4];
  const float* bias = (const float*)d_in[5];
  float* out = (float*)d_out;

  char* ws = (char*)d_ws;
  const size_t OFF_E    = 0;
  const size_t OFF_WXT  = OFF_E    + (size_t)VOCAB * FOURH * 2;   // 40,960,000
  const size_t OFF_WHT  = OFF_WXT  + (size_t)FOURH * DIM * 2;     // +2 MiB
  const size_t OFF_WE16 = OFF_WHT  + (size_t)FOURH * DIM * 2;     // +2 MiB
  const size_t OFF_HBUF = OFF_WE16 + (size_t)VOCAB * DIM * 2;     // +10.24 MB
  const size_t OFF_FLG  = OFF_HBUF + (size_t)2 * N_B * HID * 4;   // +256 KiB
  // flags: SBLK*WAVES*FLGSTR u32 = 32 KiB

  u16* E    = (u16*)(ws + OFF_E);
  u16* WxT  = (u16*)(ws + OFF_WXT);
  u16* WhT  = (u16*)(ws + OFF_WHT);
  u16* We16 = (u16*)(ws + OFF_WE16);
  u32* hbuf = (u32*)(ws + OFF_HBUF);
  u32* flg  = (u32*)(ws + OFF_FLG);

  hipLaunchKernelGGL(k_transpose, dim3(1024),   dim3(256), 0, stream, Wx, Wh, WxT, WhT);
  hipLaunchKernelGGL(k_wemb,      dim3(10000),  dim3(256), 0, stream, Wemb, We16);
  hipLaunchKernelGGL(k_init,      dim3(32),     dim3(256), 0, stream, flg);
  hipLaunchKernelGGL(k_egemm,     dim3(16, 79), dim3(256), 0, stream, We16, WxT, bias, E);
  hipLaunchKernelGGL(k_scan,      dim3(SBLK),   dim3(256), 0, stream, cap, E, WhT, h0, hbuf, flg, out);
}